// Round 2
// baseline (332.544 us; speedup 1.0000x reference)
//
#include <hip/hip_runtime.h>

typedef __attribute__((ext_vector_type(4))) float f32x4;
typedef __attribute__((ext_vector_type(8))) short bf16x8;

#define NEDGE 100000
#define NNODE 10000
#define INV40f 0.15811388300841897f
#define INV120f 0.09128709291752769f

__device__ inline short f2bf(float f) {
    unsigned u = __builtin_bit_cast(unsigned, f);
    u = (u + 0x7fffu + ((u >> 16) & 1u)) >> 16;
    return (short)u;
}

__global__ void zero_f32(float* __restrict__ p, int n) {
    int i = blockIdx.x * 256 + threadIdx.x;
    if (i < n) p[i] = 0.0f;
}

// fc1_w [64k][64n] f32 -> fc1_wt [n][k] bf16 ; fc2_w [64k][1600c] f32 -> fc2_wt [c][k] bf16
__global__ void prep_weights(const float* __restrict__ fc1_w,
                             const float* __restrict__ fc2_w,
                             short* __restrict__ fc1_wt,
                             short* __restrict__ fc2_wt) {
    int t = blockIdx.x * 256 + threadIdx.x;   // 1664*64 threads exactly
    int col = t >> 6, k = t & 63;
    if (col < 64) {
        fc1_wt[col * 64 + k] = f2bf(fc1_w[k * 64 + col]);
    } else {
        int c = col - 64;
        fc2_wt[c * 64 + k] = f2bf(fc2_w[k * 1600 + c]);
    }
}

#define MFMA16(A,B,C) __builtin_amdgcn_mfma_f32_16x16x32_bf16((A),(B),(C),0,0,0)

// CSR=true : outbuf = tp_out[E][56] streaming store, hist = int histogram of src
// CSR=false: outbuf = sums (atomic scatter), cntf = float count (round-1 behavior)
template<bool CSR>
__global__ __launch_bounds__(256) void edge_fused(
    const float* __restrict__ node_attr,
    const float* __restrict__ edge_attr,
    const float* __restrict__ edge_sh,
    const int*   __restrict__ edge_index,
    const float* __restrict__ fc1_b,
    const float* __restrict__ fc2_b,
    const short* __restrict__ fc1_wt,
    const short* __restrict__ fc2_wt,
    float* __restrict__ outbuf,
    float* __restrict__ cntf,
    int*   __restrict__ hist)
{
    __shared__ __align__(16) char h_s[4096];   // h [32][64] bf16, XOR-swizzled
    __shared__ float xbuf[32*57];
    __shared__ float shb[32*4];
    __shared__ float c00s[32*33];   // INV40*s0*x0[u]
    __shared__ float cb1s[32*33];   // INV40*x0[u]
    __shared__ float c10s[32*25];   // INV40*s0*x1[u][i]
    __shared__ float c11s[32*9];    // INV120*dot(x1[u],s1)
    __shared__ float tp0s[32*33];   // out0 accum
    __shared__ float tb1s[32*9];    // b1 accum
    __shared__ float tb2s[32*25];   // b2 accum
    __shared__ int srcs[32];

    const int tid  = threadIdx.x;
    const int lane = tid & 63;
    const int wid  = tid >> 6;
    const int l15  = lane & 15;
    const int lg   = lane >> 4;
    const int e0   = blockIdx.x * 32;

    // ---------- phase 0: gather node rows (dst), edge_sh, src ids ----------
    {
        const int r = tid >> 3, q = tid & 7;
        const int dst = edge_index[NEDGE + e0 + r];
        #pragma unroll
        for (int j = 0; j < 7; j++)
            xbuf[r*57 + q*7 + j] = node_attr[dst*56 + q*7 + j];
        if (tid < 32) {
            const int s = edge_index[e0 + tid];
            srcs[tid] = s;
            if (CSR) atomicAdd(&hist[s], 1);
            else     unsafeAtomicAdd(&cntf[s], 1.0f);
            shb[tid*4+0] = edge_sh[(e0+tid)*4+0];
            shb[tid*4+1] = edge_sh[(e0+tid)*4+1];
            shb[tid*4+2] = edge_sh[(e0+tid)*4+2];
            shb[tid*4+3] = edge_sh[(e0+tid)*4+3];
        }
    }
    __syncthreads();

    // ---------- phase 1: coefficient tables + zero tp accumulators ----------
    {
        const int r = tid >> 3, q = tid & 7;
        const float s0 = shb[r*4+0];
        const float sx = shb[r*4+1], sy = shb[r*4+2], sz = shb[r*4+3];
        #pragma unroll
        for (int j = 0; j < 4; j++) {
            const int u = q*4 + j;
            const float x0 = xbuf[r*57 + u];
            c00s[r*33+u] = INV40f * s0 * x0;
            cb1s[r*33+u] = INV40f * x0;
            tp0s[r*33+u] = 0.0f;
        }
        const float xa = xbuf[r*57 + 32 + q*3 + 0];
        const float xb = xbuf[r*57 + 32 + q*3 + 1];
        const float xc = xbuf[r*57 + 32 + q*3 + 2];
        c10s[r*25 + q*3 + 0] = INV40f * s0 * xa;
        c10s[r*25 + q*3 + 1] = INV40f * s0 * xb;
        c10s[r*25 + q*3 + 2] = INV40f * s0 * xc;
        c11s[r*9 + q] = INV120f * (xa*sx + xb*sy + xc*sz);
        tb1s[r*9 + q] = 0.0f;
        tb2s[r*25 + q*3 + 0] = 0.0f;
        tb2s[r*25 + q*3 + 1] = 0.0f;
        tb2s[r*25 + q*3 + 2] = 0.0f;
    }
    __syncthreads();

    // ---------- phase 2: fc1 via MFMA -> h (relu, bf16) into swizzled LDS ----------
    {
        bf16x8 a00, a01, a10, a11;
        {
            const float* p = edge_attr + (size_t)(e0 + l15) * 64 + lg*8;
            #pragma unroll
            for (int i = 0; i < 8; i++) a00[i] = f2bf(p[i]);
            #pragma unroll
            for (int i = 0; i < 8; i++) a01[i] = f2bf(p[32 + i]);
            p = edge_attr + (size_t)(e0 + 16 + l15) * 64 + lg*8;
            #pragma unroll
            for (int i = 0; i < 8; i++) a10[i] = f2bf(p[i]);
            #pragma unroll
            for (int i = 0; i < 8; i++) a11[i] = f2bf(p[32 + i]);
        }
        const bf16x8 b0 = *(const bf16x8*)(fc1_wt + (wid*16 + l15)*64 + lg*8);
        const bf16x8 b1 = *(const bf16x8*)(fc1_wt + (wid*16 + l15)*64 + 32 + lg*8);
        const float bias = fc1_b[wid*16 + l15];
        const int j = wid*16 + l15;
        f32x4 c0 = {0.f,0.f,0.f,0.f}, c1 = {0.f,0.f,0.f,0.f};
        c0 = MFMA16(a00, b0, c0);  c0 = MFMA16(a01, b1, c0);
        c1 = MFMA16(a10, b0, c1);  c1 = MFMA16(a11, b1, c1);
        #pragma unroll
        for (int reg = 0; reg < 4; reg++) {
            int row = lg*4 + reg;
            float v = fmaxf(c0[reg] + bias, 0.0f);
            *(short*)(h_s + ((row*128 + j*2) ^ ((row & 7) << 4))) = f2bf(v);
            row += 16;
            v = fmaxf(c1[reg] + bias, 0.0f);
            *(short*)(h_s + ((row*128 + j*2) ^ ((row & 7) << 4))) = f2bf(v);
        }
    }
    __syncthreads();

    // ---------- phase 3: load H A-fragments (reused across all 25 N-frags) ----------
    bf16x8 h00, h01, h10, h11;
    {
        int row = l15;
        h00 = *(const bf16x8*)(h_s + ((row*128 +  0 + lg*16) ^ ((row & 7) << 4)));
        h01 = *(const bf16x8*)(h_s + ((row*128 + 64 + lg*16) ^ ((row & 7) << 4)));
        row = 16 + l15;
        h10 = *(const bf16x8*)(h_s + ((row*128 +  0 + lg*16) ^ ((row & 7) << 4)));
        h11 = *(const bf16x8*)(h_s + ((row*128 + 64 + lg*16) ^ ((row & 7) << 4)));
    }

    // ---------- phase 4: fc2 MFMA + fused tensor-product consume ----------
    float acc0[2][4] = {{0,0,0,0},{0,0,0,0}};
    float ab1 [2][4] = {{0,0,0,0},{0,0,0,0}};
    float ab2 [2][4][3] = {};
    const short* pB0 = fc2_wt + l15*64 + lg*8;
    const int lg4 = lg*4;

    // region w00: nf = wid + 4*ii, ii in [0,16)   -> out0, u = (wid>>1)+2*ii, slot = wid&1
    #pragma unroll 4
    for (int ii = 0; ii < 16; ii++) {
        const int nf = wid + 4*ii;
        const bf16x8 b0 = *(const bf16x8*)(pB0 + nf*1024);
        const bf16x8 b1 = *(const bf16x8*)(pB0 + nf*1024 + 32);
        const float bias = fc2_b[nf*16 + l15];
        f32x4 c0 = {0.f,0.f,0.f,0.f}, c1 = {0.f,0.f,0.f,0.f};
        c0 = MFMA16(h00, b0, c0);  c0 = MFMA16(h01, b1, c0);
        c1 = MFMA16(h10, b0, c1);  c1 = MFMA16(h11, b1, c1);
        const int u = (wid >> 1) + 2*ii;
        #pragma unroll
        for (int reg = 0; reg < 4; reg++) {
            acc0[0][reg] += c00s[(lg4+reg)*33 + u]      * (c0[reg] + bias);
            acc0[1][reg] += c00s[(16+lg4+reg)*33 + u]   * (c1[reg] + bias);
        }
    }
    // region w01: nf = wid + 64 + 4*ii, ii in [0,4) -> b1, u = 2*(wid+4*ii) + (l15>>3)
    #pragma unroll
    for (int ii = 0; ii < 4; ii++) {
        const int nf = wid + 64 + 4*ii;
        const bf16x8 b0 = *(const bf16x8*)(pB0 + nf*1024);
        const bf16x8 b1 = *(const bf16x8*)(pB0 + nf*1024 + 32);
        const float bias = fc2_b[nf*16 + l15];
        f32x4 c0 = {0.f,0.f,0.f,0.f}, c1 = {0.f,0.f,0.f,0.f};
        c0 = MFMA16(h00, b0, c0);  c0 = MFMA16(h01, b1, c0);
        c1 = MFMA16(h10, b0, c1);  c1 = MFMA16(h11, b1, c1);
        const int u = 2*(wid + 4*ii) + (l15 >> 3);
        #pragma unroll
        for (int reg = 0; reg < 4; reg++) {
            ab1[0][reg] += cb1s[(lg4+reg)*33 + u]    * (c0[reg] + bias);
            ab1[1][reg] += cb1s[(16+lg4+reg)*33 + u] * (c1[reg] + bias);
        }
    }
    // region w10: nf = wid + 80 -> b2, u = 2*wid + (l15>>3)
    {
        const int nf = wid + 80;
        const bf16x8 b0 = *(const bf16x8*)(pB0 + nf*1024);
        const bf16x8 b1 = *(const bf16x8*)(pB0 + nf*1024 + 32);
        const float bias = fc2_b[nf*16 + l15];
        f32x4 c0 = {0.f,0.f,0.f,0.f}, c1 = {0.f,0.f,0.f,0.f};
        c0 = MFMA16(h00, b0, c0);  c0 = MFMA16(h01, b1, c0);
        c1 = MFMA16(h10, b0, c1);  c1 = MFMA16(h11, b1, c1);
        const int u = 2*wid + (l15 >> 3);
        #pragma unroll
        for (int reg = 0; reg < 4; reg++) {
            const float v0 = c0[reg] + bias, v1 = c1[reg] + bias;
            #pragma unroll
            for (int i = 0; i < 3; i++) {
                ab2[0][reg][i] += c10s[(lg4+reg)*25 + u*3 + i]    * v0;
                ab2[1][reg][i] += c10s[(16+lg4+reg)*25 + u*3 + i] * v1;
            }
        }
    }
    // region w11: nf = wid + 84 + 4*ii, ii in [0,4) -> out0, u = (wid>>1)+2*ii
    #pragma unroll
    for (int ii = 0; ii < 4; ii++) {
        const int nf = wid + 84 + 4*ii;
        const bf16x8 b0 = *(const bf16x8*)(pB0 + nf*1024);
        const bf16x8 b1 = *(const bf16x8*)(pB0 + nf*1024 + 32);
        const float bias = fc2_b[nf*16 + l15];
        f32x4 c0 = {0.f,0.f,0.f,0.f}, c1 = {0.f,0.f,0.f,0.f};
        c0 = MFMA16(h00, b0, c0);  c0 = MFMA16(h01, b1, c0);
        c1 = MFMA16(h10, b0, c1);  c1 = MFMA16(h11, b1, c1);
        const int u = (wid >> 1) + 2*ii;
        #pragma unroll
        for (int reg = 0; reg < 4; reg++) {
            acc0[0][reg] += c11s[(lg4+reg)*9 + u]    * (c0[reg] + bias);
            acc0[1][reg] += c11s[(16+lg4+reg)*9 + u] * (c1[reg] + bias);
        }
    }

    // ---------- reduce partials into LDS tp arrays ----------
    {
        const int slot16 = (wid & 1) << 4;
        #pragma unroll
        for (int mf = 0; mf < 2; mf++) {
            #pragma unroll
            for (int reg = 0; reg < 4; reg++) {
                const int r = mf*16 + lg4 + reg;
                atomicAdd(&tp0s[r*33 + slot16 + l15], acc0[mf][reg]);
                atomicAdd(&tb1s[r*9  + (l15 & 7)],    ab1[mf][reg]);
                atomicAdd(&tb2s[r*25 + (l15&7)*3 + 0], ab2[mf][reg][0]);
                atomicAdd(&tb2s[r*25 + (l15&7)*3 + 1], ab2[mf][reg][1]);
                atomicAdd(&tb2s[r*25 + (l15&7)*3 + 2], ab2[mf][reg][2]);
            }
        }
    }
    __syncthreads();

    // ---------- emit per-edge tp rows (CSR: coalesced store; else atomic scatter) ----------
    #pragma unroll
    for (int j = 0; j < 7; j++) {
        const int idx = j*256 + tid;        // 0..1791 = 32 edges * 56, coalesced per instr
        const int r = idx / 56;
        const int c = idx - r*56;
        float val;
        if (c < 32) {
            val = tp0s[r*33 + c];
        } else {
            const int d = c - 32;
            const int w = d / 3, i = d - w*3;
            val = shb[r*4 + 1 + i] * tb1s[r*9 + w] + tb2s[r*25 + d];
        }
        if (CSR) outbuf[(size_t)e0*56 + idx] = val;
        else     unsafeAtomicAdd(&outbuf[(size_t)srcs[r]*56 + c], val);
    }
}

// exclusive prefix scan of hist[10000] -> offsets, cursor (single block, 256 thr)
__global__ __launch_bounds__(256) void scan_hist(const int* __restrict__ hist,
                                                 int* __restrict__ offsets,
                                                 int* __restrict__ cursor) {
    __shared__ int part[256];
    const int t = threadIdx.x;
    const int n0 = t * 40;
    int s = 0;
    for (int j = 0; j < 40; j++) { const int n = n0 + j; s += (n < NNODE) ? hist[n] : 0; }
    part[t] = s;
    __syncthreads();
    for (int d = 1; d < 256; d <<= 1) {
        const int v = (t >= d) ? part[t - d] : 0;
        __syncthreads();
        part[t] += v;
        __syncthreads();
    }
    int run = part[t] - s;   // exclusive base
    for (int j = 0; j < 40; j++) {
        const int n = n0 + j;
        if (n < NNODE) { offsets[n] = run; cursor[n] = run; run += hist[n]; }
    }
}

__global__ __launch_bounds__(256) void fill_perm(const int* __restrict__ edge_index,
                                                 int* __restrict__ cursor,
                                                 int* __restrict__ perm) {
    const int e = blockIdx.x * 256 + threadIdx.x;
    if (e < NEDGE) {
        const int s = edge_index[e];
        const int p = atomicAdd(&cursor[s], 1);
        perm[p] = e;
    }
}

// gather-based segment mean + residual + BN partial stats (CSR path)
__global__ __launch_bounds__(256) void node_agg(
    const float* __restrict__ tp_out, const int* __restrict__ hist,
    const int* __restrict__ offsets, const int* __restrict__ perm,
    const float* __restrict__ node_attr, float* __restrict__ out,
    float* __restrict__ stats)
{
    __shared__ float part[72];
    const int tid = threadIdx.x;
    if (tid < 72) part[tid] = 0.0f;
    __syncthreads();
    const int n = blockIdx.x * 32 + (tid >> 3);
    const int q = tid & 7;
    if (n < NNODE) {
        const int deg = hist[n], st = offsets[n];
        float acc[7] = {0,0,0,0,0,0,0};
        for (int k = 0; k < deg; k++) {
            const float* row = tp_out + (size_t)perm[st + k] * 56 + q*7;
            #pragma unroll
            for (int j = 0; j < 7; j++) acc[j] += row[j];
        }
        const float inv = 1.0f / fmaxf((float)deg, 1.0f);
        #pragma unroll
        for (int j = 0; j < 7; j++) {
            const int c = q*7 + j;
            const float val = acc[j] * inv + node_attr[(size_t)n*56 + c];
            out[(size_t)n*56 + c] = val;
            if (c < 32) {
                atomicAdd(&part[c], val);
                atomicAdd(&part[32 + c], val*val);
            } else {
                atomicAdd(&part[64 + (c-32)/3], val*val);
            }
        }
    }
    __syncthreads();
    if (tid < 72) unsafeAtomicAdd(&stats[tid], part[tid]);
}

// fallback (round-1): out_pre = sums/max(cnt,1) + node_attr ; partial BN stats
__global__ __launch_bounds__(256) void node_pre(
    const float* __restrict__ sums, const float* __restrict__ cnt,
    const float* __restrict__ node_attr, float* __restrict__ out,
    float* __restrict__ stats)
{
    __shared__ float part[72];
    const int tid = threadIdx.x;
    if (tid < 72) part[tid] = 0.0f;
    __syncthreads();
    const int c = tid & 63, nsub = tid >> 6;
    if (c < 56) {
        #pragma unroll
        for (int rep = 0; rep < 8; rep++) {
            const int n = blockIdx.x*32 + nsub + rep*4;
            if (n < NNODE) {
                const float cc = cnt[n];
                const float inv = 1.0f / fmaxf(cc, 1.0f);
                const float val = sums[(size_t)n*56 + c] * inv + node_attr[(size_t)n*56 + c];
                out[(size_t)n*56 + c] = val;
                if (c < 32) {
                    atomicAdd(&part[c], val);
                    atomicAdd(&part[32 + c], val*val);
                } else {
                    atomicAdd(&part[64 + (c-32)/3], val*val);
                }
            }
        }
    }
    __syncthreads();
    if (tid < 72) unsafeAtomicAdd(&stats[tid], part[tid]);
}

__global__ __launch_bounds__(256) void node_norm(
    float* __restrict__ out, const float* __restrict__ stats,
    const float* __restrict__ g0, const float* __restrict__ b0,
    const float* __restrict__ g1)
{
    const int id = blockIdx.x*256 + threadIdx.x;
    if (id >= NNODE*56) return;
    const int c = id % 56;
    float val = out[id];
    if (c < 32) {
        const float m   = stats[c]      * (1.0f / NNODE);
        const float ex2 = stats[32 + c] * (1.0f / NNODE);
        const float var = ex2 - m*m;
        val = (val - m) * rsqrtf(var + 1e-5f) * g0[c] + b0[c];
    } else {
        const int v = (c - 32) / 3;
        const float vn = stats[64 + v] * (1.0f / (3.0f * NNODE));
        val = val * rsqrtf(vn + 1e-5f) * g1[v];
    }
    out[id] = val;
}

extern "C" void kernel_launch(void* const* d_in, const int* in_sizes, int n_in,
                              void* d_out, int out_size, void* d_ws, size_t ws_size,
                              hipStream_t stream) {
    const float* node_attr = (const float*)d_in[0];
    const float* edge_attr = (const float*)d_in[1];
    const float* edge_sh   = (const float*)d_in[2];
    const int*   edge_index= (const int*)  d_in[3];
    const float* fc1_w     = (const float*)d_in[4];
    const float* fc1_b     = (const float*)d_in[5];
    const float* fc2_w     = (const float*)d_in[6];
    const float* fc2_b     = (const float*)d_in[7];
    const float* g0        = (const float*)d_in[8];
    const float* b0        = (const float*)d_in[9];
    const float* g1        = (const float*)d_in[10];
    float* out = (float*)d_out;

    char* ws = (char*)d_ws;
    const bool use_csr = (ws_size >= 23133312ull);

    if (use_csr) {
        // layout: stats(288) | hist(40000) | offsets(40000) | cursor(40000) |
        //         perm(400000) | pad(32) | fc1_wt(8192) | fc2_wt(204800) | tp_out(22.4MB)
        float* stats   = (float*)(ws + 0);
        int*   hist    = (int*)  (ws + 288);
        int*   offsets = (int*)  (ws + 40288);
        int*   cursor  = (int*)  (ws + 80288);
        int*   perm    = (int*)  (ws + 120288);
        short* fc1_wt  = (short*)(ws + 520320);
        short* fc2_wt  = (short*)(ws + 528512);
        float* tp_out  = (float*)(ws + 733312);

        zero_f32<<<40, 256, 0, stream>>>((float*)ws, 10072);   // stats + hist
        prep_weights<<<416, 256, 0, stream>>>(fc1_w, fc2_w, fc1_wt, fc2_wt);
        edge_fused<true><<<3125, 256, 0, stream>>>(node_attr, edge_attr, edge_sh, edge_index,
                                                   fc1_b, fc2_b, fc1_wt, fc2_wt,
                                                   tp_out, nullptr, hist);
        scan_hist<<<1, 256, 0, stream>>>(hist, offsets, cursor);
        fill_perm<<<391, 256, 0, stream>>>(edge_index, cursor, perm);
        node_agg<<<313, 256, 0, stream>>>(tp_out, hist, offsets, perm, node_attr, out, stats);
        node_norm<<<2188, 256, 0, stream>>>(out, stats, g0, b0, g1);
    } else {
        // round-1 fallback layout
        float* sums  = (float*)ws;                        // 560000 f32
        float* cntf  = sums + 560000;                     // 10000 f32
        float* stats = cntf + 10000;                      // 72 f32
        short* fc1_wt = (short*)(ws + 2280288);
        short* fc2_wt = (short*)(ws + 2288480);

        zero_f32<<<2227, 256, 0, stream>>>(sums, 570072);
        prep_weights<<<416, 256, 0, stream>>>(fc1_w, fc2_w, fc1_wt, fc2_wt);
        edge_fused<false><<<3125, 256, 0, stream>>>(node_attr, edge_attr, edge_sh, edge_index,
                                                    fc1_b, fc2_b, fc1_wt, fc2_wt,
                                                    sums, cntf, nullptr);
        node_pre<<<313, 256, 0, stream>>>(sums, cntf, node_attr, out, stats);
        node_norm<<<2188, 256, 0, stream>>>(out, stats, g0, b0, g1);
    }
}

// Round 3
// 326.103 us; speedup vs baseline: 1.0198x; 1.0198x over previous
//
#include <hip/hip_runtime.h>

typedef __attribute__((ext_vector_type(4))) float f32x4;
typedef __attribute__((ext_vector_type(8))) short bf16x8;

#define NEDGE 100000
#define NNODE 10000
#define INV40f 0.15811388300841897f
#define INV120f 0.09128709291752769f

__device__ inline short f2bf(float f) {
    unsigned u = __builtin_bit_cast(unsigned, f);
    u = (u + 0x7fffu + ((u >> 16) & 1u)) >> 16;
    return (short)u;
}

__global__ void zero_f32(float* __restrict__ p, int n) {
    int i = blockIdx.x * 256 + threadIdx.x;
    if (i < n) p[i] = 0.0f;
}

// fc1_w [64k][64n] f32 -> fc1_wt [n][k] bf16 (coalesced read, tiny strided write)
__global__ void prep_fc1(const float* __restrict__ fc1_w, short* __restrict__ fc1_wt) {
    int t = blockIdx.x * 256 + threadIdx.x;   // 16 blocks * 256 = 4096 exactly
    fc1_wt[(t & 63) * 64 + (t >> 6)] = f2bf(fc1_w[t]);
}

// fc2_w [64k][1600c] f32 -> fc2_wt [c][k] bf16 (coalesced read; strided 2B write absorbed by L2)
__global__ void prep_fc2(const float* __restrict__ fc2_w, short* __restrict__ fc2_wt) {
    int c = blockIdx.x * 256 + threadIdx.x;
    int k = blockIdx.y;
    if (c < 1600) fc2_wt[c * 64 + k] = f2bf(fc2_w[k * 1600 + c]);
}

#define MFMA16(A,B,C) __builtin_amdgcn_mfma_f32_16x16x32_bf16((A),(B),(C),0,0,0)

__global__ __launch_bounds__(256, 8) void edge_fused(
    const float* __restrict__ node_attr,
    const float* __restrict__ edge_attr,
    const float* __restrict__ edge_sh,
    const int*   __restrict__ edge_index,
    const float* __restrict__ fc1_b,
    const float* __restrict__ fc2_b,
    const short* __restrict__ fc1_wt,
    const short* __restrict__ fc2_wt,
    float* __restrict__ tp_out,
    int*   __restrict__ hist)
{
    // LDS budget trimmed to ~26KB -> 6 blocks/CU.
    __shared__ __align__(16) char h_s[4096];       // h [32][64] bf16, XOR-swizzled
    __shared__ __align__(16) float blob[2144];     // xbuf[32*57] (ph0-1)  UNION  tp0s/tb1s/tb2s (ph2+)
    __shared__ float shb[32*4];
    __shared__ float c00s[32*33];   // INV40*s0*x0[u]
    __shared__ float cb1s[32*33];   // INV40*x0[u]
    __shared__ float c10s[32*25];   // INV40*s0*x1[u][i]
    __shared__ float c11s[32*9];    // INV120*dot(x1[u],s1)

    float* xbuf = blob;             // [32*57], dead after phase 1
    float* tp0s = blob;             // [32*33]
    float* tb1s = blob + 1056;      // [32*9]
    float* tb2s = blob + 1344;      // [32*25]  (1344+800 = 2144)

    const int tid  = threadIdx.x;
    const int lane = tid & 63;
    const int wid  = tid >> 6;
    const int l15  = lane & 15;
    const int lg   = lane >> 4;
    const int e0   = blockIdx.x * 32;

    // ---------- phase 0: gather node rows (dst) vectorized, edge_sh, hist ----------
    {
        const int r = tid >> 3, q = tid & 7;
        const int dst = edge_index[NEDGE + e0 + r];
        if (q < 7) {
            const f32x4 v1 = *(const f32x4*)(node_attr + (size_t)dst*56 + q*4);
            const f32x4 v2 = *(const f32x4*)(node_attr + (size_t)dst*56 + (q+7)*4);
            #pragma unroll
            for (int j = 0; j < 4; j++) {
                xbuf[r*57 + q*4 + j]      = v1[j];
                xbuf[r*57 + 28 + q*4 + j] = v2[j];
            }
        }
        if (tid < 32) {
            atomicAdd(&hist[edge_index[e0 + tid]], 1);
            shb[tid*4+0] = edge_sh[(e0+tid)*4+0];
            shb[tid*4+1] = edge_sh[(e0+tid)*4+1];
            shb[tid*4+2] = edge_sh[(e0+tid)*4+2];
            shb[tid*4+3] = edge_sh[(e0+tid)*4+3];
        }
    }
    __syncthreads();

    // ---------- phase 1: coefficient tables (last read of xbuf) ----------
    {
        const int r = tid >> 3, q = tid & 7;
        const float s0 = shb[r*4+0];
        const float sx = shb[r*4+1], sy = shb[r*4+2], sz = shb[r*4+3];
        float x0v[4];
        #pragma unroll
        for (int j = 0; j < 4; j++) x0v[j] = xbuf[r*57 + q*4 + j];
        const float xa = xbuf[r*57 + 32 + q*3 + 0];
        const float xb = xbuf[r*57 + 32 + q*3 + 1];
        const float xc = xbuf[r*57 + 32 + q*3 + 2];
        __syncthreads();   // all xbuf reads done before tables overwrite-safe regions
        #pragma unroll
        for (int j = 0; j < 4; j++) {
            const int u = q*4 + j;
            c00s[r*33+u] = INV40f * s0 * x0v[j];
            cb1s[r*33+u] = INV40f * x0v[j];
        }
        c10s[r*25 + q*3 + 0] = INV40f * s0 * xa;
        c10s[r*25 + q*3 + 1] = INV40f * s0 * xb;
        c10s[r*25 + q*3 + 2] = INV40f * s0 * xc;
        c11s[r*9 + q] = INV120f * (xa*sx + xb*sy + xc*sz);
    }
    __syncthreads();

    // ---------- phase 2: zero tp accumulators (alias of xbuf) + fc1 MFMA -> h ----------
    for (int i = tid; i < 2144; i += 256) blob[i] = 0.0f;
    {
        bf16x8 a00, a01, a10, a11;
        {
            const float* p = edge_attr + (size_t)(e0 + l15) * 64 + lg*8;
            #pragma unroll
            for (int i = 0; i < 8; i++) a00[i] = f2bf(p[i]);
            #pragma unroll
            for (int i = 0; i < 8; i++) a01[i] = f2bf(p[32 + i]);
            p = edge_attr + (size_t)(e0 + 16 + l15) * 64 + lg*8;
            #pragma unroll
            for (int i = 0; i < 8; i++) a10[i] = f2bf(p[i]);
            #pragma unroll
            for (int i = 0; i < 8; i++) a11[i] = f2bf(p[32 + i]);
        }
        const bf16x8 b0 = *(const bf16x8*)(fc1_wt + (wid*16 + l15)*64 + lg*8);
        const bf16x8 b1 = *(const bf16x8*)(fc1_wt + (wid*16 + l15)*64 + 32 + lg*8);
        const float bias = fc1_b[wid*16 + l15];
        const int j = wid*16 + l15;
        f32x4 c0 = {0.f,0.f,0.f,0.f}, c1 = {0.f,0.f,0.f,0.f};
        c0 = MFMA16(a00, b0, c0);  c0 = MFMA16(a01, b1, c0);
        c1 = MFMA16(a10, b0, c1);  c1 = MFMA16(a11, b1, c1);
        #pragma unroll
        for (int reg = 0; reg < 4; reg++) {
            int row = lg*4 + reg;
            float v = fmaxf(c0[reg] + bias, 0.0f);
            *(short*)(h_s + ((row*128 + j*2) ^ ((row & 7) << 4))) = f2bf(v);
            row += 16;
            v = fmaxf(c1[reg] + bias, 0.0f);
            *(short*)(h_s + ((row*128 + j*2) ^ ((row & 7) << 4))) = f2bf(v);
        }
    }
    __syncthreads();

    // ---------- phase 3: load H A-fragments (reused across all 25 N-frags) ----------
    bf16x8 h00, h01, h10, h11;
    {
        int row = l15;
        h00 = *(const bf16x8*)(h_s + ((row*128 +  0 + lg*16) ^ ((row & 7) << 4)));
        h01 = *(const bf16x8*)(h_s + ((row*128 + 64 + lg*16) ^ ((row & 7) << 4)));
        row = 16 + l15;
        h10 = *(const bf16x8*)(h_s + ((row*128 +  0 + lg*16) ^ ((row & 7) << 4)));
        h11 = *(const bf16x8*)(h_s + ((row*128 + 64 + lg*16) ^ ((row & 7) << 4)));
    }

    // ---------- phase 4: fc2 MFMA + fused tensor-product consume ----------
    float acc0[2][4] = {{0,0,0,0},{0,0,0,0}};
    float ab1 [2][4] = {{0,0,0,0},{0,0,0,0}};
    float ab2 [2][4][3] = {};
    const short* pB0 = fc2_wt + l15*64 + lg*8;
    const int lg4 = lg*4;

    // region w00: nf = wid + 4*ii, ii in [0,16) -> out0, u = (wid>>1)+2*ii
    #pragma unroll 4
    for (int ii = 0; ii < 16; ii++) {
        const int nf = wid + 4*ii;
        const bf16x8 b0 = *(const bf16x8*)(pB0 + nf*1024);
        const bf16x8 b1 = *(const bf16x8*)(pB0 + nf*1024 + 32);
        const float bias = fc2_b[nf*16 + l15];
        f32x4 c0 = {0.f,0.f,0.f,0.f}, c1 = {0.f,0.f,0.f,0.f};
        c0 = MFMA16(h00, b0, c0);  c0 = MFMA16(h01, b1, c0);
        c1 = MFMA16(h10, b0, c1);  c1 = MFMA16(h11, b1, c1);
        const int u = (wid >> 1) + 2*ii;
        #pragma unroll
        for (int reg = 0; reg < 4; reg++) {
            acc0[0][reg] += c00s[(lg4+reg)*33 + u]      * (c0[reg] + bias);
            acc0[1][reg] += c00s[(16+lg4+reg)*33 + u]   * (c1[reg] + bias);
        }
    }
    // region w01: nf = wid + 64 + 4*ii, ii in [0,4) -> b1, u = 2*(wid+4*ii) + (l15>>3)
    #pragma unroll
    for (int ii = 0; ii < 4; ii++) {
        const int nf = wid + 64 + 4*ii;
        const bf16x8 b0 = *(const bf16x8*)(pB0 + nf*1024);
        const bf16x8 b1 = *(const bf16x8*)(pB0 + nf*1024 + 32);
        const float bias = fc2_b[nf*16 + l15];
        f32x4 c0 = {0.f,0.f,0.f,0.f}, c1 = {0.f,0.f,0.f,0.f};
        c0 = MFMA16(h00, b0, c0);  c0 = MFMA16(h01, b1, c0);
        c1 = MFMA16(h10, b0, c1);  c1 = MFMA16(h11, b1, c1);
        const int u = 2*(wid + 4*ii) + (l15 >> 3);
        #pragma unroll
        for (int reg = 0; reg < 4; reg++) {
            ab1[0][reg] += cb1s[(lg4+reg)*33 + u]    * (c0[reg] + bias);
            ab1[1][reg] += cb1s[(16+lg4+reg)*33 + u] * (c1[reg] + bias);
        }
    }
    // region w10: nf = wid + 80 -> b2, u = 2*wid + (l15>>3)
    {
        const int nf = wid + 80;
        const bf16x8 b0 = *(const bf16x8*)(pB0 + nf*1024);
        const bf16x8 b1 = *(const bf16x8*)(pB0 + nf*1024 + 32);
        const float bias = fc2_b[nf*16 + l15];
        f32x4 c0 = {0.f,0.f,0.f,0.f}, c1 = {0.f,0.f,0.f,0.f};
        c0 = MFMA16(h00, b0, c0);  c0 = MFMA16(h01, b1, c0);
        c1 = MFMA16(h10, b0, c1);  c1 = MFMA16(h11, b1, c1);
        const int u = 2*wid + (l15 >> 3);
        #pragma unroll
        for (int reg = 0; reg < 4; reg++) {
            const float v0 = c0[reg] + bias, v1 = c1[reg] + bias;
            #pragma unroll
            for (int i = 0; i < 3; i++) {
                ab2[0][reg][i] += c10s[(lg4+reg)*25 + u*3 + i]    * v0;
                ab2[1][reg][i] += c10s[(16+lg4+reg)*25 + u*3 + i] * v1;
            }
        }
    }
    // region w11: nf = wid + 84 + 4*ii, ii in [0,4) -> out0, u = (wid>>1)+2*ii
    #pragma unroll
    for (int ii = 0; ii < 4; ii++) {
        const int nf = wid + 84 + 4*ii;
        const bf16x8 b0 = *(const bf16x8*)(pB0 + nf*1024);
        const bf16x8 b1 = *(const bf16x8*)(pB0 + nf*1024 + 32);
        const float bias = fc2_b[nf*16 + l15];
        f32x4 c0 = {0.f,0.f,0.f,0.f}, c1 = {0.f,0.f,0.f,0.f};
        c0 = MFMA16(h00, b0, c0);  c0 = MFMA16(h01, b1, c0);
        c1 = MFMA16(h10, b0, c1);  c1 = MFMA16(h11, b1, c1);
        const int u = (wid >> 1) + 2*ii;
        #pragma unroll
        for (int reg = 0; reg < 4; reg++) {
            acc0[0][reg] += c11s[(lg4+reg)*9 + u]    * (c0[reg] + bias);
            acc0[1][reg] += c11s[(16+lg4+reg)*9 + u] * (c1[reg] + bias);
        }
    }

    // ---------- reduce partials into LDS tp arrays (zeroed before phase-2->3 barrier) ----------
    {
        const int slot16 = (wid & 1) << 4;
        #pragma unroll
        for (int mf = 0; mf < 2; mf++) {
            #pragma unroll
            for (int reg = 0; reg < 4; reg++) {
                const int r = mf*16 + lg4 + reg;
                atomicAdd(&tp0s[r*33 + slot16 + l15], acc0[mf][reg]);
                atomicAdd(&tb1s[r*9  + (l15 & 7)],    ab1[mf][reg]);
                atomicAdd(&tb2s[r*25 + (l15&7)*3 + 0], ab2[mf][reg][0]);
                atomicAdd(&tb2s[r*25 + (l15&7)*3 + 1], ab2[mf][reg][1]);
                atomicAdd(&tb2s[r*25 + (l15&7)*3 + 2], ab2[mf][reg][2]);
            }
        }
    }
    __syncthreads();

    // ---------- emit per-edge tp rows, coalesced ----------
    #pragma unroll
    for (int j = 0; j < 7; j++) {
        const int idx = j*256 + tid;        // 0..1791 = 32 edges * 56
        const int r = idx / 56;
        const int c = idx - r*56;
        float val;
        if (c < 32) {
            val = tp0s[r*33 + c];
        } else {
            const int d = c - 32;
            const int w = d / 3, i = d - w*3;
            val = shb[r*4 + 1 + i] * tb1s[r*9 + w] + tb2s[r*25 + d];
        }
        tp_out[(size_t)e0*56 + idx] = val;
    }
}

// exclusive prefix scan of hist[10000] -> offsets, cursor (single block, 256 thr)
__global__ __launch_bounds__(256) void scan_hist(const int* __restrict__ hist,
                                                 int* __restrict__ offsets,
                                                 int* __restrict__ cursor) {
    __shared__ int part[256];
    const int t = threadIdx.x;
    const int n0 = t * 40;
    int s = 0;
    for (int j = 0; j < 40; j++) { const int n = n0 + j; s += (n < NNODE) ? hist[n] : 0; }
    part[t] = s;
    __syncthreads();
    for (int d = 1; d < 256; d <<= 1) {
        const int v = (t >= d) ? part[t - d] : 0;
        __syncthreads();
        part[t] += v;
        __syncthreads();
    }
    int run = part[t] - s;   // exclusive base
    for (int j = 0; j < 40; j++) {
        const int n = n0 + j;
        if (n < NNODE) { offsets[n] = run; cursor[n] = run; run += hist[n]; }
    }
}

__global__ __launch_bounds__(256) void fill_perm(const int* __restrict__ edge_index,
                                                 int* __restrict__ cursor,
                                                 int* __restrict__ perm) {
    const int e = blockIdx.x * 256 + threadIdx.x;
    if (e < NEDGE) {
        const int s = edge_index[e];
        const int p = atomicAdd(&cursor[s], 1);
        perm[p] = e;
    }
}

// gather-based segment mean + residual + BN partial stats (16 threads/node, f32x4)
__global__ __launch_bounds__(256) void node_agg(
    const float* __restrict__ tp_out, const int* __restrict__ hist,
    const int* __restrict__ offsets, const int* __restrict__ perm,
    const float* __restrict__ node_attr, float* __restrict__ out,
    float* __restrict__ stats)
{
    __shared__ float part[72];
    const int tid = threadIdx.x;
    if (tid < 72) part[tid] = 0.0f;
    __syncthreads();
    const int n = blockIdx.x * 16 + (tid >> 4);   // 16 nodes/block
    const int q = tid & 15;                       // 14 active chunks of 4 floats
    if (n < NNODE && q < 14) {
        const int deg = hist[n], st = offsets[n];
        f32x4 acc = {0.f,0.f,0.f,0.f};
        for (int k = 0; k < deg; k++) {
            const float* row = tp_out + (size_t)perm[st + k] * 56;
            acc += *(const f32x4*)(row + q*4);
        }
        const float inv = 1.0f / fmaxf((float)deg, 1.0f);
        const int c0 = q*4;
        const f32x4 res = *(const f32x4*)(node_attr + (size_t)n*56 + c0);
        f32x4 val;
        #pragma unroll
        for (int j = 0; j < 4; j++) {
            val[j] = acc[j]*inv + res[j];
            const int c = c0 + j;
            if (c < 32) {
                atomicAdd(&part[c], val[j]);
                atomicAdd(&part[32 + c], val[j]*val[j]);
            } else {
                atomicAdd(&part[64 + (c-32)/3], val[j]*val[j]);
            }
        }
        *(f32x4*)(out + (size_t)n*56 + c0) = val;
    }
    __syncthreads();
    if (tid < 72) unsafeAtomicAdd(&stats[tid], part[tid]);
}

__global__ __launch_bounds__(256) void node_norm(
    float* __restrict__ out, const float* __restrict__ stats,
    const float* __restrict__ g0, const float* __restrict__ b0,
    const float* __restrict__ g1)
{
    const int id = blockIdx.x*256 + threadIdx.x;
    if (id >= NNODE*56) return;
    const int c = id % 56;
    float val = out[id];
    if (c < 32) {
        const float m   = stats[c]      * (1.0f / NNODE);
        const float ex2 = stats[32 + c] * (1.0f / NNODE);
        const float var = ex2 - m*m;
        val = (val - m) * rsqrtf(var + 1e-5f) * g0[c] + b0[c];
    } else {
        const int v = (c - 32) / 3;
        const float vn = stats[64 + v] * (1.0f / (3.0f * NNODE));
        val = val * rsqrtf(vn + 1e-5f) * g1[v];
    }
    out[id] = val;
}

extern "C" void kernel_launch(void* const* d_in, const int* in_sizes, int n_in,
                              void* d_out, int out_size, void* d_ws, size_t ws_size,
                              hipStream_t stream) {
    const float* node_attr = (const float*)d_in[0];
    const float* edge_attr = (const float*)d_in[1];
    const float* edge_sh   = (const float*)d_in[2];
    const int*   edge_index= (const int*)  d_in[3];
    const float* fc1_w     = (const float*)d_in[4];
    const float* fc1_b     = (const float*)d_in[5];
    const float* fc2_w     = (const float*)d_in[6];
    const float* fc2_b     = (const float*)d_in[7];
    const float* g0        = (const float*)d_in[8];
    const float* b0        = (const float*)d_in[9];
    const float* g1        = (const float*)d_in[10];
    float* out = (float*)d_out;

    char* ws = (char*)d_ws;
    // layout: stats(288) | hist(40000) | offsets(40000) | cursor(40000) |
    //         perm(400000) | pad | fc1_wt(8192) | fc2_wt(204800) | tp_out(22.4MB)
    float* stats   = (float*)(ws + 0);
    int*   hist    = (int*)  (ws + 288);
    int*   offsets = (int*)  (ws + 40288);
    int*   cursor  = (int*)  (ws + 80288);
    int*   perm    = (int*)  (ws + 120288);
    short* fc1_wt  = (short*)(ws + 520320);
    short* fc2_wt  = (short*)(ws + 528512);
    float* tp_out  = (float*)(ws + 733312);

    zero_f32<<<40, 256, 0, stream>>>((float*)ws, 10072);   // stats + hist
    prep_fc1<<<16, 256, 0, stream>>>(fc1_w, fc1_wt);
    prep_fc2<<<dim3(7, 64), 256, 0, stream>>>(fc2_w, fc2_wt);
    edge_fused<<<3125, 256, 0, stream>>>(node_attr, edge_attr, edge_sh, edge_index,
                                         fc1_b, fc2_b, fc1_wt, fc2_wt, tp_out, hist);
    scan_hist<<<1, 256, 0, stream>>>(hist, offsets, cursor);
    fill_perm<<<391, 256, 0, stream>>>(edge_index, cursor, perm);
    node_agg<<<625, 256, 0, stream>>>(tp_out, hist, offsets, perm, node_attr, out, stats);
    node_norm<<<2188, 256, 0, stream>>>(out, stats, g0, b0, g1);
}

// Round 4
// 240.595 us; speedup vs baseline: 1.3822x; 1.3554x over previous
//
#include <hip/hip_runtime.h>

typedef __attribute__((ext_vector_type(4))) float f32x4;
typedef __attribute__((ext_vector_type(8))) short bf16x8;

#define NEDGE 100000
#define NNODE 10000
#define INV40f 0.15811388300841897f
#define INV120f 0.09128709291752769f

__device__ inline short f2bf(float f) {
    unsigned u = __builtin_bit_cast(unsigned, f);
    u = (u + 0x7fffu + ((u >> 16) & 1u)) >> 16;
    return (short)u;
}

__global__ void zero_f32(float* __restrict__ p, int n) {
    int i = blockIdx.x * 256 + threadIdx.x;
    if (i < n) p[i] = 0.0f;
}

// fc1_w [64k][64n] f32 -> fc1_wt [n][k] bf16 (coalesced read, tiny strided write)
__global__ void prep_fc1(const float* __restrict__ fc1_w, short* __restrict__ fc1_wt) {
    int t = blockIdx.x * 256 + threadIdx.x;   // 16 blocks * 256 = 4096 exactly
    fc1_wt[(t & 63) * 64 + (t >> 6)] = f2bf(fc1_w[t]);
}

// fc2_w [64k][1600c] f32 -> fc2_wt [c][k] bf16 (coalesced read; strided 2B write absorbed by L2)
__global__ void prep_fc2(const float* __restrict__ fc2_w, short* __restrict__ fc2_wt) {
    int c = blockIdx.x * 256 + threadIdx.x;
    int k = blockIdx.y;
    if (c < 1600) fc2_wt[c * 64 + k] = f2bf(fc2_w[k * 1600 + c]);
}

#define MFMA16(A,B,C) __builtin_amdgcn_mfma_f32_16x16x32_bf16((A),(B),(C),0,0,0)

// One wave (64 threads) owns 16 edges end-to-end. No __syncthreads anywhere:
// all LDS is wave-private; within-wave LDS ops are in-order (lgkmcnt only).
__global__ __launch_bounds__(64, 4) void edge_fused(
    const float* __restrict__ node_attr,
    const float* __restrict__ edge_attr,
    const float* __restrict__ edge_sh,
    const int*   __restrict__ edge_index,
    const float* __restrict__ fc1_b,
    const float* __restrict__ fc2_b,
    const short* __restrict__ fc1_wt,
    const short* __restrict__ fc2_wt,
    float* __restrict__ tp_out,
    int*   __restrict__ hist)
{
    __shared__ __align__(16) char lds[10496];
    float* xbuf = (float*)lds;            // [16][60] f32 (3840B) — aliases h_s (read-then-write safe, in-order)
    char*  h_s  = lds;                    // [16 rows][128B] bf16, XOR-swizzled (2048B)
    float* c00s = (float*)(lds + 3840);   // [16][33]  INV40*s0*x0[u]
    float* cb1s = (float*)(lds + 5952);   // [16][33]  INV40*x0[u]
    float* c10s = (float*)(lds + 8064);   // [16][25]  INV40*s0*x1[u][i]
    float* c11s = (float*)(lds + 9664);   // [16][9]   INV120*dot(x1[u],s1)
    float* shb  = (float*)(lds + 10240);  // [16][4]

    const int tid = threadIdx.x;          // 0..63, one wave
    const int l15 = tid & 15;
    const int lg  = tid >> 4;
    const int lg4 = lg * 4;
    const int e0  = blockIdx.x * 16;

    // ---- early loads: edge meta (lanes 0..15) ----
    int dst_r = 0, src_r = 0; f32x4 sh_r = {0.f,0.f,0.f,0.f};
    if (tid < 16) {
        dst_r = edge_index[NEDGE + e0 + tid];
        src_r = edge_index[e0 + tid];
        sh_r  = *(const f32x4*)(edge_sh + (size_t)(e0 + tid)*4);
    }

    // ---- fc1 A loads (streaming HBM) issued early ----
    const float* pa = edge_attr + (size_t)(e0 + l15)*64 + lg*8;
    const f32x4 va0 = *(const f32x4*)(pa);
    const f32x4 va1 = *(const f32x4*)(pa + 4);
    const f32x4 va2 = *(const f32x4*)(pa + 32);
    const f32x4 va3 = *(const f32x4*)(pa + 36);

    if (tid < 16) {
        atomicAdd(&hist[src_r], 1);
        *(f32x4*)(shb + tid*4) = sh_r;
    }

    // ---- gather node_attr[dst] -> xbuf (wave-private) ----
    const int grow = tid >> 2, gq = tid & 3;
    const int dstm = __shfl(dst_r, grow, 64);
    const float* nap = node_attr + (size_t)dstm*56;
    {
        const f32x4 g0 = *(const f32x4*)(nap + gq*4);
        const f32x4 g1 = *(const f32x4*)(nap + 16 + gq*4);
        const f32x4 g2 = *(const f32x4*)(nap + 32 + gq*4);
        *(f32x4*)(xbuf + grow*60 + gq*4)      = g0;
        *(f32x4*)(xbuf + grow*60 + 16 + gq*4) = g1;
        *(f32x4*)(xbuf + grow*60 + 32 + gq*4) = g2;
        if (gq < 2) {
            const f32x4 g3 = *(const f32x4*)(nap + 48 + gq*4);
            *(f32x4*)(xbuf + grow*60 + 48 + gq*4) = g3;
        }
    }

    // ---- coefficient tables (reads xbuf, writes tables; all wave-local) ----
    {
        const float s0 = shb[grow*4+0], sx = shb[grow*4+1], sy = shb[grow*4+2], sz = shb[grow*4+3];
        #pragma unroll
        for (int j = 0; j < 8; j++) {
            const int u = gq*8 + j;
            const float x0 = xbuf[grow*60 + u];
            c00s[grow*33 + u] = INV40f * s0 * x0;
            cb1s[grow*33 + u] = INV40f * x0;
        }
        #pragma unroll
        for (int t = 0; t < 2; t++) {
            const int w = gq*2 + t;
            const float xa = xbuf[grow*60 + 32 + w*3 + 0];
            const float xb = xbuf[grow*60 + 32 + w*3 + 1];
            const float xc = xbuf[grow*60 + 32 + w*3 + 2];
            c10s[grow*25 + w*3 + 0] = INV40f * s0 * xa;
            c10s[grow*25 + w*3 + 1] = INV40f * s0 * xb;
            c10s[grow*25 + w*3 + 2] = INV40f * s0 * xc;
            c11s[grow*9 + w] = INV120f * (xa*sx + xb*sy + xc*sz);
        }
    }

    // ---- fc1: A frags from registers ----
    bf16x8 a0, a1;
    #pragma unroll
    for (int i = 0; i < 4; i++) {
        a0[i]   = f2bf(va0[i]);
        a0[4+i] = f2bf(va1[i]);
        a1[i]   = f2bf(va2[i]);
        a1[4+i] = f2bf(va3[i]);
    }

    // fc1 MFMA (M=16) + relu -> h into swizzled LDS (overwrites xbuf region; program order safe)
    #pragma unroll
    for (int nf0 = 0; nf0 < 4; nf0++) {
        const bf16x8 b0 = *(const bf16x8*)(fc1_wt + (nf0*16 + l15)*64 + lg*8);
        const bf16x8 b1 = *(const bf16x8*)(fc1_wt + (nf0*16 + l15)*64 + 32 + lg*8);
        const float bias = fc1_b[nf0*16 + l15];
        f32x4 c = {bias, bias, bias, bias};
        c = MFMA16(a0, b0, c);
        c = MFMA16(a1, b1, c);
        #pragma unroll
        for (int reg = 0; reg < 4; reg++) {
            const int row = lg4 + reg;
            *(short*)(h_s + ((row*128 + (nf0*16 + l15)*2) ^ ((row & 7) << 4))) =
                f2bf(fmaxf(c[reg], 0.0f));
        }
    }

    // ---- read h A-frags (transpose via LDS; wave-local, lgkmcnt only) ----
    const bf16x8 ha0 = *(const bf16x8*)(h_s + ((l15*128 +      lg*16) ^ ((l15 & 7) << 4)));
    const bf16x8 ha1 = *(const bf16x8*)(h_s + ((l15*128 + 64 + lg*16) ^ ((l15 & 7) << 4)));

    // ---- fc2 + fused TP consume: 100 independent iterations, no barriers ----
    const short* pB = fc2_wt + l15*64 + lg*8;
    const int usel = l15 >> 3;

    float acc0[2][4] = {{0,0,0,0},{0,0,0,0}};
    // region w00: nf 0..63 ; u = nf>>1, out-col = (nf&1)*16 + l15
    #pragma unroll 4
    for (int nf = 0; nf < 64; nf++) {
        const bf16x8 b0 = *(const bf16x8*)(pB + nf*1024);
        const bf16x8 b1 = *(const bf16x8*)(pB + nf*1024 + 32);
        const float bias = fc2_b[nf*16 + l15];
        f32x4 c = {bias, bias, bias, bias};
        c = MFMA16(ha0, b0, c);
        c = MFMA16(ha1, b1, c);
        const int u = nf >> 1, hi = nf & 1;
        #pragma unroll
        for (int reg = 0; reg < 4; reg++)
            acc0[hi][reg] += c00s[(lg4 + reg)*33 + u] * c[reg];
    }
    // region w01: nf 64..79 ; u = nfl*2 + (l15>>3), w = l15&7
    float ab1[4] = {0,0,0,0};
    #pragma unroll 4
    for (int nfl = 0; nfl < 16; nfl++) {
        const int nf = 64 + nfl;
        const bf16x8 b0 = *(const bf16x8*)(pB + nf*1024);
        const bf16x8 b1 = *(const bf16x8*)(pB + nf*1024 + 32);
        const float bias = fc2_b[nf*16 + l15];
        f32x4 c = {bias, bias, bias, bias};
        c = MFMA16(ha0, b0, c);
        c = MFMA16(ha1, b1, c);
        const int u = nfl*2 + usel;
        #pragma unroll
        for (int reg = 0; reg < 4; reg++)
            ab1[reg] += cb1s[(lg4 + reg)*33 + u] * c[reg];
    }
    // region w10: nf 80..83 ; u = nfl*2 + (l15>>3), w = l15&7
    float b2[4][3] = {};
    #pragma unroll
    for (int nfl = 0; nfl < 4; nfl++) {
        const int nf = 80 + nfl;
        const bf16x8 b0 = *(const bf16x8*)(pB + nf*1024);
        const bf16x8 b1 = *(const bf16x8*)(pB + nf*1024 + 32);
        const float bias = fc2_b[nf*16 + l15];
        f32x4 c = {bias, bias, bias, bias};
        c = MFMA16(ha0, b0, c);
        c = MFMA16(ha1, b1, c);
        const int u = nfl*2 + usel;
        #pragma unroll
        for (int reg = 0; reg < 4; reg++) {
            #pragma unroll
            for (int i = 0; i < 3; i++)
                b2[reg][i] += c10s[(lg4 + reg)*25 + u*3 + i] * c[reg];
        }
    }
    // region w11: nf 84..99 ; u = nfl>>1, out-col = (nfl&1)*16 + l15
    #pragma unroll 4
    for (int nfl = 0; nfl < 16; nfl++) {
        const int nf = 84 + nfl;
        const bf16x8 b0 = *(const bf16x8*)(pB + nf*1024);
        const bf16x8 b1 = *(const bf16x8*)(pB + nf*1024 + 32);
        const float bias = fc2_b[nf*16 + l15];
        f32x4 c = {bias, bias, bias, bias};
        c = MFMA16(ha0, b0, c);
        c = MFMA16(ha1, b1, c);
        const int u = nfl >> 1, hi = nfl & 1;
        #pragma unroll
        for (int reg = 0; reg < 4; reg++)
            acc0[hi][reg] += c11s[(lg4 + reg)*9 + u] * c[reg];
    }

    // ---- emit: out0 direct from registers ----
    #pragma unroll
    for (int reg = 0; reg < 4; reg++) {
        const size_t eoff = (size_t)(e0 + lg4 + reg) * 56;
        tp_out[eoff + l15]      = acc0[0][reg];
        tp_out[eoff + 16 + l15] = acc0[1][reg];
    }
    // ---- out1: fold the two u-halves (lanes l15 and l15^8), then store ----
    #pragma unroll
    for (int reg = 0; reg < 4; reg++) {
        ab1[reg] += __shfl_xor(ab1[reg], 8, 64);
        #pragma unroll
        for (int i = 0; i < 3; i++)
            b2[reg][i] += __shfl_xor(b2[reg][i], 8, 64);
    }
    if (l15 < 8) {
        #pragma unroll
        for (int reg = 0; reg < 4; reg++) {
            const int r = lg4 + reg;
            const float s1x = shb[r*4+1], s1y = shb[r*4+2], s1z = shb[r*4+3];
            const size_t eoff = (size_t)(e0 + r) * 56 + 32 + l15*3;
            tp_out[eoff + 0] = s1x*ab1[reg] + b2[reg][0];
            tp_out[eoff + 1] = s1y*ab1[reg] + b2[reg][1];
            tp_out[eoff + 2] = s1z*ab1[reg] + b2[reg][2];
        }
    }
}

// exclusive prefix scan of hist[10000] -> offsets, cursor (single block, 256 thr)
__global__ __launch_bounds__(256) void scan_hist(const int* __restrict__ hist,
                                                 int* __restrict__ offsets,
                                                 int* __restrict__ cursor) {
    __shared__ int part[256];
    const int t = threadIdx.x;
    const int n0 = t * 40;
    int s = 0;
    for (int j = 0; j < 40; j++) { const int n = n0 + j; s += (n < NNODE) ? hist[n] : 0; }
    part[t] = s;
    __syncthreads();
    for (int d = 1; d < 256; d <<= 1) {
        const int v = (t >= d) ? part[t - d] : 0;
        __syncthreads();
        part[t] += v;
        __syncthreads();
    }
    int run = part[t] - s;   // exclusive base
    for (int j = 0; j < 40; j++) {
        const int n = n0 + j;
        if (n < NNODE) { offsets[n] = run; cursor[n] = run; run += hist[n]; }
    }
}

__global__ __launch_bounds__(256) void fill_perm(const int* __restrict__ edge_index,
                                                 int* __restrict__ cursor,
                                                 int* __restrict__ perm) {
    const int e = blockIdx.x * 256 + threadIdx.x;
    if (e < NEDGE) {
        const int s = edge_index[e];
        const int p = atomicAdd(&cursor[s], 1);
        perm[p] = e;
    }
}

// gather-based segment mean + residual + BN partial stats (16 threads/node, f32x4)
__global__ __launch_bounds__(256) void node_agg(
    const float* __restrict__ tp_out, const int* __restrict__ hist,
    const int* __restrict__ offsets, const int* __restrict__ perm,
    const float* __restrict__ node_attr, float* __restrict__ out,
    float* __restrict__ stats)
{
    __shared__ float part[72];
    const int tid = threadIdx.x;
    if (tid < 72) part[tid] = 0.0f;
    __syncthreads();
    const int n = blockIdx.x * 16 + (tid >> 4);   // 16 nodes/block
    const int q = tid & 15;                       // 14 active chunks of 4 floats
    if (n < NNODE && q < 14) {
        const int deg = hist[n], st = offsets[n];
        f32x4 acc = {0.f,0.f,0.f,0.f};
        for (int k = 0; k < deg; k++) {
            const float* row = tp_out + (size_t)perm[st + k] * 56;
            acc += *(const f32x4*)(row + q*4);
        }
        const float inv = 1.0f / fmaxf((float)deg, 1.0f);
        const int c0 = q*4;
        const f32x4 res = *(const f32x4*)(node_attr + (size_t)n*56 + c0);
        f32x4 val;
        #pragma unroll
        for (int j = 0; j < 4; j++) {
            val[j] = acc[j]*inv + res[j];
            const int c = c0 + j;
            if (c < 32) {
                atomicAdd(&part[c], val[j]);
                atomicAdd(&part[32 + c], val[j]*val[j]);
            } else {
                atomicAdd(&part[64 + (c-32)/3], val[j]*val[j]);
            }
        }
        *(f32x4*)(out + (size_t)n*56 + c0) = val;
    }
    __syncthreads();
    if (tid < 72) unsafeAtomicAdd(&stats[tid], part[tid]);
}

__global__ __launch_bounds__(256) void node_norm(
    float* __restrict__ out, const float* __restrict__ stats,
    const float* __restrict__ g0, const float* __restrict__ b0,
    const float* __restrict__ g1)
{
    const int id = blockIdx.x*256 + threadIdx.x;
    if (id >= NNODE*56) return;
    const int c = id % 56;
    float val = out[id];
    if (c < 32) {
        const float m   = stats[c]      * (1.0f / NNODE);
        const float ex2 = stats[32 + c] * (1.0f / NNODE);
        const float var = ex2 - m*m;
        val = (val - m) * rsqrtf(var + 1e-5f) * g0[c] + b0[c];
    } else {
        const int v = (c - 32) / 3;
        const float vn = stats[64 + v] * (1.0f / (3.0f * NNODE));
        val = val * rsqrtf(vn + 1e-5f) * g1[v];
    }
    out[id] = val;
}

extern "C" void kernel_launch(void* const* d_in, const int* in_sizes, int n_in,
                              void* d_out, int out_size, void* d_ws, size_t ws_size,
                              hipStream_t stream) {
    const float* node_attr = (const float*)d_in[0];
    const float* edge_attr = (const float*)d_in[1];
    const float* edge_sh   = (const float*)d_in[2];
    const int*   edge_index= (const int*)  d_in[3];
    const float* fc1_w     = (const float*)d_in[4];
    const float* fc1_b     = (const float*)d_in[5];
    const float* fc2_w     = (const float*)d_in[6];
    const float* fc2_b     = (const float*)d_in[7];
    const float* g0        = (const float*)d_in[8];
    const float* b0        = (const float*)d_in[9];
    const float* g1        = (const float*)d_in[10];
    float* out = (float*)d_out;

    char* ws = (char*)d_ws;
    // layout: stats(288) | hist(40000) | offsets(40000) | cursor(40000) |
    //         perm(400000) | pad | fc1_wt(8192) | fc2_wt(204800) | tp_out(22.4MB)
    float* stats   = (float*)(ws + 0);
    int*   hist    = (int*)  (ws + 288);
    int*   offsets = (int*)  (ws + 40288);
    int*   cursor  = (int*)  (ws + 80288);
    int*   perm    = (int*)  (ws + 120288);
    short* fc1_wt  = (short*)(ws + 520320);
    short* fc2_wt  = (short*)(ws + 528512);
    float* tp_out  = (float*)(ws + 733312);

    zero_f32<<<40, 256, 0, stream>>>((float*)ws, 10072);   // stats + hist
    prep_fc1<<<16, 256, 0, stream>>>(fc1_w, fc1_wt);
    prep_fc2<<<dim3(7, 64), 256, 0, stream>>>(fc2_w, fc2_wt);
    edge_fused<<<6250, 64, 0, stream>>>(node_attr, edge_attr, edge_sh, edge_index,
                                        fc1_b, fc2_b, fc1_wt, fc2_wt, tp_out, hist);
    scan_hist<<<1, 256, 0, stream>>>(hist, offsets, cursor);
    fill_perm<<<391, 256, 0, stream>>>(edge_index, cursor, perm);
    node_agg<<<625, 256, 0, stream>>>(tp_out, hist, offsets, perm, node_attr, out, stats);
    node_norm<<<2188, 256, 0, stream>>>(out, stats, g0, b0, g1);
}